// Round 1
// 481.116 us; speedup vs baseline: 1.1116x; 1.1116x over previous
//
#include <hip/hip_runtime.h>
#include <math.h>
#include <stdint.h>

// Problem constants (fixed by setup_inputs)
#define S_DIM 128
#define B_DIM 256
#define L_DIM 512
#define K_DIM 8
#define T_IN  16
#define STEPS 103                      // 128 - 16 - (8 + 0 + 1)
#define DENOM (K_DIM * STEPS * B_DIM)  // 210944
#define PRED_K ((size_t)STEPS * B_DIM * L_DIM)   // elems per k slab (13,500,416)

typedef __attribute__((ext_vector_type(8))) short short8;  // 8 bf16 (MFMA A/B frag)
typedef __attribute__((ext_vector_type(4))) float f32x4;   // MFMA C/D frag

// round-to-nearest-even fp32 -> bf16
__device__ __forceinline__ short f2bf(float f) {
    unsigned u = __float_as_uint(f);
    u += 0x7FFFu + ((u >> 16) & 1u);
    return (short)(u >> 16);
}

// async global->LDS, 16B per lane; LDS dest = wave-uniform base + lane*16
__device__ __forceinline__ void load_lds16(const void* g, void* l) {
    __builtin_amdgcn_global_load_lds(
        (const __attribute__((address_space(1))) unsigned*)g,
        (__attribute__((address_space(3))) unsigned*)l, 16, 0, 0);
}

// One fused fp32->bf16 convert over all three inputs (grid-stride, float4)
#define ENC4 ((S_DIM * B_DIM * L_DIM) / 4)          // 4,194,304
#define CTX4 ((STEPS * B_DIM * L_DIM) / 4)          // 3,375,104
#define WK4  ((K_DIM * L_DIM * L_DIM) / 4)          //   524,288
__global__ void convert_all(const float* __restrict__ enc_in, const float* __restrict__ ctx_in,
                            const float* __restrict__ wk_in, short* __restrict__ enc_out,
                            short* __restrict__ ctx_out, short* __restrict__ wk_out) {
    for (int i = blockIdx.x * blockDim.x + threadIdx.x; i < ENC4 + CTX4 + WK4;
         i += gridDim.x * blockDim.x) {
        const float4* src; short4* dst; int j;
        if (i < ENC4)             { src = (const float4*)enc_in; dst = (short4*)enc_out; j = i; }
        else if (i < ENC4 + CTX4) { src = (const float4*)ctx_in; dst = (short4*)ctx_out; j = i - ENC4; }
        else                      { src = (const float4*)wk_in;  dst = (short4*)wk_out;  j = i - ENC4 - CTX4; }
        const float4 v = src[j];
        short4 o;
        o.x = f2bf(v.x); o.y = f2bf(v.y); o.z = f2bf(v.z); o.w = f2bf(v.w);
        dst[j] = o;
    }
}

// ---------------------------------------------------------------------------
// bf16 MFMA GEMM (NT), k-batched, BK=64.
// Grid SWAPPED to (4g, 206): blockIdx.x enumerates (kin,cn) so the 32
// consecutive blocks share one 128 KB A-panel (L2-resident) instead of
// re-streaming the 27 MB A matrix 32x from L3; B (4 MB total) stays L2-hot.
// Bijective XCD-chunk swizzle (m204) gives each XCD a contiguous bm range.
// 128x128 tile, 4 waves 2x2, 4x4 16x16x32 frags, 32 MFMA per barrier-pair.
// Staging: 64-elem rows, global_load_lds(16B), XOR chunk swizzle
// ch8 ^ (row&7) (pattern verified, absmax 0 / bank-conflict 0).
// ---------------------------------------------------------------------------
__global__ __launch_bounds__(256)
void gemm_bf16(const short* __restrict__ A, const short* __restrict__ W,
               short* __restrict__ C) {
    __shared__ short As[128 * 64];   // 16 KB
    __shared__ short Bs[128 * 64];   // 16 KB
    // ---- block decode: x = (kin,cn) fast, y = bm slow, XCD-chunked ----
    const int gx  = gridDim.x;                  // 4g, always a power of two
    const int nwg = gx * gridDim.y;
    const int id  = blockIdx.y * gx + blockIdx.x;
    const int q8 = nwg >> 3, r8 = nwg & 7;
    const int xcd = id & 7;
    const int lin = (xcd < r8 ? xcd * (q8 + 1) : r8 * (q8 + 1) + (xcd - r8) * q8)
                  + (id >> 3);
    const int lgx = 31 - __clz(gx);
    const int bm = lin >> lgx;
    const int xc = lin & (gx - 1);
    const int kin = xc >> 2, cn = xc & 3;

    const int t = threadIdx.x;
    const int w = t >> 6, lane = t & 63, quad = lane >> 4, l15 = lane & 15;
    const int wm = w & 1, wn = w >> 1;
    const int rl8 = lane >> 3, ch8 = lane & 7;

    const short* Ab = A + (size_t)bm * 128 * L_DIM;
    const short* Wb = W + ((size_t)kin * L_DIM + cn * 128) * L_DIM;
    short* Ck = C + kin * PRED_K;

    f32x4 acc[4][4] = {};

    for (int kt = 0; kt < L_DIM; kt += 64) {
        #pragma unroll
        for (int q = 0; q < 4; q++) {               // 128 rows each of A and B
            const int rb = w * 32 + q * 8;
            const int row = rb + rl8;
            const int ch = ch8 ^ (row & 7);
            load_lds16(Ab + (size_t)row * L_DIM + kt + ch * 8, &As[rb * 64]);
            load_lds16(Wb + (size_t)row * L_DIM + kt + ch * 8, &Bs[rb * 64]);
        }
        __syncthreads();
        #pragma unroll
        for (int k2 = 0; k2 < 2; k2++) {
            short8 a[4], b[4];
            #pragma unroll
            for (int i = 0; i < 4; i++) {
                const int m = wm * 64 + i * 16 + l15;
                a[i] = *(const short8*)&As[m * 64 + ((k2 * 4 + quad) ^ (m & 7)) * 8];
                const int n = wn * 64 + i * 16 + l15;
                b[i] = *(const short8*)&Bs[n * 64 + ((k2 * 4 + quad) ^ (n & 7)) * 8];
            }
            #pragma unroll
            for (int i = 0; i < 4; i++)
                #pragma unroll
                for (int j = 0; j < 4; j++)
                    acc[i][j] = __builtin_amdgcn_mfma_f32_16x16x32_bf16(a[i], b[j], acc[i][j], 0, 0, 0);
        }
        __syncthreads();
    }
    // C/D layout: col = lane&15, row = quad*4 + reg  [verified]
    #pragma unroll
    for (int i = 0; i < 4; i++)
        #pragma unroll
        for (int r = 0; r < 4; r++) {
            const int row = bm * 128 + wm * 64 + i * 16 + quad * 4 + r;
            short* Cr = Ck + (size_t)row * L_DIM + cn * 128 + wn * 64 + l15;
            #pragma unroll
            for (int j = 0; j < 4; j++)
                Cr[j * 16] = f2bf(acc[i][j][r]);
        }
}

// ---------------------------------------------------------------------------
// Fused sim + log-softmax + argmax, k-batched, LDS double-buffered.
// Grid (103, 2, g): block (s, bt, kin), rows b = bt*128..+127, cols 0..255.
// 512 thr = 8 waves (mi = w&1, nj = w>>1), wave tile 64x64, 4x4 frags.
// PIPELINE (T3-minimal): stage tile kt+1 into buf^1 via global_load_lds
// BEFORE computing tile kt, then ONE __syncthreads per tile (its implicit
// vmcnt(0) drain lands after the 32 MFMAs instead of before them).
// Barriers/block: 16 -> 9. LDS 102.4 KB -> 1 block/CU (in-block pipelining
// replaces TLP that wasn't covering the stalls anyway: MfmaUtil was 10%).
// Layout/swizzle/frag math byte-identical to the verified version.
// ---------------------------------------------------------------------------
__global__ __launch_bounds__(512)
void sim_phase(const short* __restrict__ encbf, const short* __restrict__ pred,
               const int k0, unsigned long long* __restrict__ col_best,
               float* __restrict__ diag_accum) {
    __shared__ short Es[2][128 * 64];  // 32 KB
    __shared__ short Ps[2][256 * 64];  // 64 KB
    __shared__ float rmx[128][4];      // per-(row, nj-wave) max partials
    __shared__ float rsx[128][4];      // per-(row, nj-wave) expsum partials
    __shared__ float dred[8];          // per-wave diag partials
    const int s = blockIdx.x, bt = blockIdx.y, kin = blockIdx.z;
    const int k = k0 + kin;
    const int t = threadIdx.x, w = t >> 6, lane = t & 63;
    const int quad = lane >> 4, l15 = lane & 15;
    const int mi = w & 1, nj = w >> 1;
    const int rl8 = lane >> 3, ch8 = lane & 7;

    const short* Eb = encbf + ((size_t)(T_IN + 1 + k + s) * B_DIM + bt * 128) * L_DIM;
    const short* Pb = pred + kin * PRED_K + (size_t)s * B_DIM * L_DIM;

    // hoisted per-thread staging addresses (source carries the XOR chunk swizzle)
    const short* esrc[2]; int edst[2];
    #pragma unroll
    for (int q = 0; q < 2; q++) {
        const int rb = w * 16 + q * 8, row = rb + rl8;
        esrc[q] = Eb + (size_t)row * L_DIM + (ch8 ^ (row & 7)) * 8;
        edst[q] = rb * 64;
    }
    const short* psrc[4]; int pdst[4];
    #pragma unroll
    for (int q = 0; q < 4; q++) {
        const int rb = w * 32 + q * 8, row = rb + rl8;
        psrc[q] = Pb + (size_t)row * L_DIM + (ch8 ^ (row & 7)) * 8;
        pdst[q] = rb * 64;
    }

    // prologue: tile 0 into buffer 0
    #pragma unroll
    for (int q = 0; q < 2; q++) load_lds16(esrc[q], &Es[0][edst[q]]);
    #pragma unroll
    for (int q = 0; q < 4; q++) load_lds16(psrc[q], &Ps[0][pdst[q]]);
    __syncthreads();

    f32x4 acc[4][4] = {};
    int cur = 0;
    #pragma unroll
    for (int kt = 0; kt < L_DIM; kt += 64) {
        if (kt + 64 < L_DIM) {   // issue next tile's loads before computing current
            #pragma unroll
            for (int q = 0; q < 2; q++)
                load_lds16(esrc[q] + kt + 64, &Es[cur ^ 1][edst[q]]);
            #pragma unroll
            for (int q = 0; q < 4; q++)
                load_lds16(psrc[q] + kt + 64, &Ps[cur ^ 1][pdst[q]]);
        }
        #pragma unroll
        for (int k2 = 0; k2 < 2; k2++) {
            short8 a[4], b[4];
            #pragma unroll
            for (int i = 0; i < 4; i++) {
                const int m = mi * 64 + i * 16 + l15;
                a[i] = *(const short8*)&Es[cur][m * 64 + ((k2 * 4 + quad) ^ (m & 7)) * 8];
                const int n = nj * 64 + i * 16 + l15;
                b[i] = *(const short8*)&Ps[cur][n * 64 + ((k2 * 4 + quad) ^ (n & 7)) * 8];
            }
            #pragma unroll
            for (int i = 0; i < 4; i++)
                #pragma unroll
                for (int j = 0; j < 4; j++)
                    acc[i][j] = __builtin_amdgcn_mfma_f32_16x16x32_bf16(a[i], b[j], acc[i][j], 0, 0, 0);
        }
        __syncthreads();   // all waves done reading [cur]; next tile's loads drained
        cur ^= 1;
    }

    // ---- E1: row max over 256 cols ----
    float rm[4][4];
    #pragma unroll
    for (int i = 0; i < 4; i++)
        #pragma unroll
        for (int r = 0; r < 4; r++) {
            float m = acc[i][0][r];
            #pragma unroll
            for (int j = 1; j < 4; j++) m = fmaxf(m, acc[i][j][r]);
            rm[i][r] = m;
        }
    #pragma unroll
    for (int off = 1; off < 16; off <<= 1)
        #pragma unroll
        for (int i = 0; i < 4; i++)
            #pragma unroll
            for (int r = 0; r < 4; r++)
                rm[i][r] = fmaxf(rm[i][r], __shfl_xor(rm[i][r], off, 64));
    if (l15 == 0)
        #pragma unroll
        for (int i = 0; i < 4; i++)
            #pragma unroll
            for (int r = 0; r < 4; r++)
                rmx[mi * 64 + i * 16 + quad * 4 + r][nj] = rm[i][r];
    __syncthreads();

    float mrow[4][4];
    #pragma unroll
    for (int i = 0; i < 4; i++)
        #pragma unroll
        for (int r = 0; r < 4; r++) {
            const f32x4 v = *(const f32x4*)rmx[mi * 64 + i * 16 + quad * 4 + r];
            mrow[i][r] = fmaxf(fmaxf(v[0], v[1]), fmaxf(v[2], v[3]));
        }

    // ---- E2: row sum of exp ----
    float rs[4][4];
    #pragma unroll
    for (int i = 0; i < 4; i++)
        #pragma unroll
        for (int r = 0; r < 4; r++) {
            float sum = 0.f;
            #pragma unroll
            for (int j = 0; j < 4; j++) sum += __expf(acc[i][j][r] - mrow[i][r]);
            rs[i][r] = sum;
        }
    #pragma unroll
    for (int off = 1; off < 16; off <<= 1)
        #pragma unroll
        for (int i = 0; i < 4; i++)
            #pragma unroll
            for (int r = 0; r < 4; r++)
                rs[i][r] += __shfl_xor(rs[i][r], off, 64);
    if (l15 == 0)
        #pragma unroll
        for (int i = 0; i < 4; i++)
            #pragma unroll
            for (int r = 0; r < 4; r++)
                rsx[mi * 64 + i * 16 + quad * 4 + r][nj] = rs[i][r];
    __syncthreads();

    float lse[4][4];
    #pragma unroll
    for (int i = 0; i < 4; i++)
        #pragma unroll
        for (int r = 0; r < 4; r++) {
            const f32x4 v = *(const f32x4*)rsx[mi * 64 + i * 16 + quad * 4 + r];
            lse[i][r] = mrow[i][r] + __logf(v[0] + v[1] + v[2] + v[3]);
        }

    // ---- E3: column argmax (packed u64: ordered-float<<32 | (255-b)) ----
    #pragma unroll
    for (int j = 0; j < 4; j++) {
        unsigned long long best = 0;
        #pragma unroll
        for (int i = 0; i < 4; i++)
            #pragma unroll
            for (int r = 0; r < 4; r++) {
                const int grow = bt * 128 + mi * 64 + i * 16 + quad * 4 + r;
                const float v = acc[i][j][r] - lse[i][r];
                unsigned int fb = __float_as_uint(v);
                fb = (fb & 0x80000000u) ? ~fb : (fb | 0x80000000u);
                const unsigned long long p =
                    ((unsigned long long)fb << 32) | (unsigned long long)(255 - grow);
                if (p > best) best = p;          // packed compare: ties -> smallest b
            }
        unsigned long long o;
        o = __shfl_xor(best, 16, 64); if (o > best) best = o;
        o = __shfl_xor(best, 32, 64); if (o > best) best = o;
        if (quad == 0)
            atomicMax(&col_best[((size_t)k * STEPS + s) * B_DIM + nj * 64 + j * 16 + l15], best);
    }

    // ---- diag logp: 1 atomic per block ----
    {
        float dv = 0.f;
        #pragma unroll
        for (int i = 0; i < 4; i++)
            #pragma unroll
            for (int j = 0; j < 4; j++)
                #pragma unroll
                for (int r = 0; r < 4; r++) {
                    const int grow = bt * 128 + mi * 64 + i * 16 + quad * 4 + r;
                    const int c = nj * 64 + j * 16 + l15;
                    if (grow == c) dv += acc[i][j][r] - lse[i][r];
                }
        #pragma unroll
        for (int off = 1; off < 64; off <<= 1) dv += __shfl_xor(dv, off, 64);
        if (lane == 0) dred[w] = dv;
    }
    __syncthreads();
    if (t == 0) {
        float dv = 0.f;
        #pragma unroll
        for (int i = 0; i < 8; i++) dv += dred[i];
        atomicAdd(diag_accum, dv);
    }
}

__global__ void count_correct(const unsigned long long* __restrict__ col_best,
                              int* __restrict__ correct_accum) {
    __shared__ int red[256];
    const int t = threadIdx.x;
    int cnt = 0;
    for (int i = blockIdx.x * 256 + t; i < DENOM; i += gridDim.x * 256) {
        const int c = i & (B_DIM - 1);
        const int b = 255 - (int)(col_best[i] & 0xFFFFFFFFull);
        cnt += (b == c) ? 1 : 0;
    }
    red[t] = cnt;
    __syncthreads();
    for (int off = 128; off > 0; off >>= 1) {
        if (t < off) red[t] += red[t + off];
        __syncthreads();
    }
    if (t == 0) atomicAdd(correct_accum, red[0]);
}

__global__ void finalize(const int* __restrict__ correct_accum,
                         const float* __restrict__ diag_accum,
                         float* __restrict__ out) {
    const float denom = (float)DENOM;
    out[0] = (float)(*correct_accum) / denom;   // accuracy
    out[1] = -(*diag_accum) / denom;            // loss
}

extern "C" void kernel_launch(void* const* d_in, const int* in_sizes, int n_in,
                              void* d_out, int out_size, void* d_ws, size_t ws_size,
                              hipStream_t stream) {
    const float* encoded_x = (const float*)d_in[0];
    const float* context   = (const float*)d_in[1];
    const float* Wk        = (const float*)d_in[2];
    float* out = (float*)d_out;

    const size_t enc_elems = (size_t)S_DIM * B_DIM * L_DIM;    // 16,777,216
    const size_t ctx_elems = (size_t)STEPS * B_DIM * L_DIM;    // 13,500,416
    const size_t wk_elems  = (size_t)K_DIM * L_DIM * L_DIM;    //  2,097,152
    const size_t pred_k_bytes = ctx_elems * 2;                 // 27.0 MB per k

    char* ws = (char*)d_ws;
    short* encbf = (short*)ws;                                          // 33.6 MB
    short* ctxbf = (short*)(ws + enc_elems * 2);                        // 27.0 MB
    short* wkbf  = (short*)(ws + (enc_elems + ctx_elems) * 2);          //  4.2 MB
    const size_t off = (enc_elems + ctx_elems + wk_elems) * 2;
    unsigned long long* col_best = (unsigned long long*)(ws + off);     // 1.69 MB
    float* diag_accum    = (float*)(ws + off + (size_t)DENOM * 8);
    int*   correct_accum = (int*)  (ws + off + (size_t)DENOM * 8 + 4);
    const size_t fixed = off + (size_t)DENOM * 8 + 64;
    short* pred = (short*)(ws + fixed);

    // g=8: single gemm + single sim dispatch. Sim is latency-bound, not
    // BW-bound -- maximize per-dispatch waves, pipeline inside the block.
    int g = K_DIM;
    while (g > 1 && fixed + (size_t)g * pred_k_bytes > ws_size) g >>= 1;

    hipMemsetAsync(col_best, 0, (size_t)DENOM * 8 + 16, stream);
    convert_all<<<2048, 256, 0, stream>>>(encoded_x, context + (size_t)T_IN * B_DIM * L_DIM,
                                          Wk, encbf, ctxbf, wkbf);

    const dim3 g1(4 * g, (STEPS * B_DIM) / 128);    // (4g, 206): x = (kin,cn)
    const dim3 g2(STEPS, 2, g);                     // (103, 2, g)
    for (int k0 = 0; k0 < K_DIM; k0 += g) {
        gemm_bf16<<<g1, 256, 0, stream>>>(ctxbf, wkbf + (size_t)k0 * L_DIM * L_DIM, pred);
        sim_phase<<<g2, 512, 0, stream>>>(encbf, pred, k0, col_best, diag_accum);
    }
    count_correct<<<64, 256, 0, stream>>>(col_best, correct_accum);
    finalize<<<1, 1, 0, stream>>>(correct_accum, diag_accum, out);
}

// Round 2
// 422.606 us; speedup vs baseline: 1.2655x; 1.1385x over previous
//
#include <hip/hip_runtime.h>
#include <math.h>
#include <stdint.h>

// Problem constants (fixed by setup_inputs)
#define S_DIM 128
#define B_DIM 256
#define L_DIM 512
#define K_DIM 8
#define T_IN  16
#define STEPS 103                      // 128 - 16 - (8 + 0 + 1)
#define DENOM (K_DIM * STEPS * B_DIM)  // 210944
#define PRED_K ((size_t)STEPS * B_DIM * L_DIM)   // elems per k slab (13,500,416)

typedef __attribute__((ext_vector_type(8))) short short8;  // 8 bf16 (MFMA A/B frag)
typedef __attribute__((ext_vector_type(4))) float f32x4;   // MFMA C/D frag

// round-to-nearest-even fp32 -> bf16
__device__ __forceinline__ short f2bf(float f) {
    unsigned u = __float_as_uint(f);
    u += 0x7FFFu + ((u >> 16) & 1u);
    return (short)(u >> 16);
}

// async global->LDS, 16B per lane; LDS dest = wave-uniform base + lane*16
__device__ __forceinline__ void load_lds16(const void* g, void* l) {
    __builtin_amdgcn_global_load_lds(
        (const __attribute__((address_space(1))) unsigned*)g,
        (__attribute__((address_space(3))) unsigned*)l, 16, 0, 0);
}

// One fused fp32->bf16 convert over all three inputs (grid-stride, float4).
// TAIL: also zeroes col_best (DENOM u64) + diag/correct (1 u64) + done (1 u64)
// -- replaces the hipMemsetAsync dispatch.
#define ENC4 ((S_DIM * B_DIM * L_DIM) / 4)          // 4,194,304
#define CTX4 ((STEPS * B_DIM * L_DIM) / 4)          // 3,375,104
#define WK4  ((K_DIM * L_DIM * L_DIM) / 4)          //   524,288
#define CV_N (ENC4 + CTX4 + WK4)
#define Z_N  (DENOM + 2)                            // u64 slots to zero
__global__ void convert_all(const float* __restrict__ enc_in, const float* __restrict__ ctx_in,
                            const float* __restrict__ wk_in, short* __restrict__ enc_out,
                            short* __restrict__ ctx_out, short* __restrict__ wk_out,
                            unsigned long long* __restrict__ zbuf) {
    for (int i = blockIdx.x * blockDim.x + threadIdx.x; i < CV_N + Z_N;
         i += gridDim.x * blockDim.x) {
        if (i >= CV_N) { zbuf[i - CV_N] = 0ull; continue; }
        const float4* src; short4* dst; int j;
        if (i < ENC4)             { src = (const float4*)enc_in; dst = (short4*)enc_out; j = i; }
        else if (i < ENC4 + CTX4) { src = (const float4*)ctx_in; dst = (short4*)ctx_out; j = i - ENC4; }
        else                      { src = (const float4*)wk_in;  dst = (short4*)wk_out;  j = i - ENC4 - CTX4; }
        const float4 v = src[j];
        short4 o;
        o.x = f2bf(v.x); o.y = f2bf(v.y); o.z = f2bf(v.z); o.w = f2bf(v.w);
        dst[j] = o;
    }
}

// ---------------------------------------------------------------------------
// bf16 MFMA GEMM (NT), k-batched, BK=64.
// Grid (4g, 206): blockIdx.x enumerates (kin,cn) so the 32 consecutive blocks
// share one 128 KB A-panel (L2-resident); B (4 MB total) stays L2-hot.
// Bijective XCD-chunk swizzle (m204). 128x128 tile, 4 waves 2x2, 4x4 frags.
// (unchanged from round 1 -- it delivered ~45 us)
// ---------------------------------------------------------------------------
__global__ __launch_bounds__(256)
void gemm_bf16(const short* __restrict__ A, const short* __restrict__ W,
               short* __restrict__ C) {
    __shared__ short As[128 * 64];   // 16 KB
    __shared__ short Bs[128 * 64];   // 16 KB
    const int gx  = gridDim.x;                  // 4g, always a power of two
    const int nwg = gx * gridDim.y;
    const int id  = blockIdx.y * gx + blockIdx.x;
    const int q8 = nwg >> 3, r8 = nwg & 7;
    const int xcd = id & 7;
    const int lin = (xcd < r8 ? xcd * (q8 + 1) : r8 * (q8 + 1) + (xcd - r8) * q8)
                  + (id >> 3);
    const int lgx = 31 - __clz(gx);
    const int bm = lin >> lgx;
    const int xc = lin & (gx - 1);
    const int kin = xc >> 2, cn = xc & 3;

    const int t = threadIdx.x;
    const int w = t >> 6, lane = t & 63, quad = lane >> 4, l15 = lane & 15;
    const int wm = w & 1, wn = w >> 1;
    const int rl8 = lane >> 3, ch8 = lane & 7;

    const short* Ab = A + (size_t)bm * 128 * L_DIM;
    const short* Wb = W + ((size_t)kin * L_DIM + cn * 128) * L_DIM;
    short* Ck = C + kin * PRED_K;

    f32x4 acc[4][4] = {};

    for (int kt = 0; kt < L_DIM; kt += 64) {
        #pragma unroll
        for (int q = 0; q < 4; q++) {               // 128 rows each of A and B
            const int rb = w * 32 + q * 8;
            const int row = rb + rl8;
            const int ch = ch8 ^ (row & 7);
            load_lds16(Ab + (size_t)row * L_DIM + kt + ch * 8, &As[rb * 64]);
            load_lds16(Wb + (size_t)row * L_DIM + kt + ch * 8, &Bs[rb * 64]);
        }
        __syncthreads();
        #pragma unroll
        for (int k2 = 0; k2 < 2; k2++) {
            short8 a[4], b[4];
            #pragma unroll
            for (int i = 0; i < 4; i++) {
                const int m = wm * 64 + i * 16 + l15;
                a[i] = *(const short8*)&As[m * 64 + ((k2 * 4 + quad) ^ (m & 7)) * 8];
                const int n = wn * 64 + i * 16 + l15;
                b[i] = *(const short8*)&Bs[n * 64 + ((k2 * 4 + quad) ^ (n & 7)) * 8];
            }
            #pragma unroll
            for (int i = 0; i < 4; i++)
                #pragma unroll
                for (int j = 0; j < 4; j++)
                    acc[i][j] = __builtin_amdgcn_mfma_f32_16x16x32_bf16(a[i], b[j], acc[i][j], 0, 0, 0);
        }
        __syncthreads();
    }
    // C/D layout: col = lane&15, row = quad*4 + reg  [verified]
    #pragma unroll
    for (int i = 0; i < 4; i++)
        #pragma unroll
        for (int r = 0; r < 4; r++) {
            const int row = bm * 128 + wm * 64 + i * 16 + quad * 4 + r;
            short* Cr = Ck + (size_t)row * L_DIM + cn * 128 + wn * 64 + l15;
            #pragma unroll
            for (int j = 0; j < 4; j++)
                Cr[j * 16] = f2bf(acc[i][j][r]);
        }
}

// ---------------------------------------------------------------------------
// Fused sim + log-softmax + argmax, k-batched, LDS double-buffered.
// ROUND 2: bt-split REMOVED. Grid (103, g): block (s, kin) computes the FULL
// 256x256 sim tile. 8 waves as 4(row)x2(col): wave tile 64x128, acc[4][8].
// Rationale: the two bt blocks staged the SAME 256x64 Ps tile -> pred L2-miss
// traffic paid 2x and only 32 MFMA amortized each barrier. Merged: staged
// pred bytes halve, 64 MFMA per barrier-pair (latency coverage ~2x).
// LDS 132 KB -> 1 block/CU. Staging/swizzle/frag math is the verified pattern.
// ---------------------------------------------------------------------------
__global__ __launch_bounds__(512, 2)
void sim_phase(const short* __restrict__ encbf, const short* __restrict__ pred,
               const int k0, unsigned long long* __restrict__ col_best,
               float* __restrict__ diag_accum) {
    __shared__ short Es[2][256 * 64];  // 64 KB
    __shared__ short Ps[2][256 * 64];  // 64 KB
    __shared__ float rmx[256][2];      // per-(row, wn-wave) max partials
    __shared__ float rsx[256][2];      // per-(row, wn-wave) expsum partials
    __shared__ float dred[8];          // per-wave diag partials
    const int s = blockIdx.x, kin = blockIdx.y;
    const int k = k0 + kin;
    const int t = threadIdx.x, w = t >> 6, lane = t & 63;
    const int quad = lane >> 4, l15 = lane & 15;
    const int wm = w & 3, wn = w >> 2;           // 4 row-waves x 2 col-waves
    const int rl8 = lane >> 3, ch8 = lane & 7;

    const short* Eb = encbf + ((size_t)(T_IN + 1 + k + s) * B_DIM) * L_DIM;
    const short* Pb = pred + kin * PRED_K + (size_t)s * B_DIM * L_DIM;

    // hoisted per-thread staging addresses (source carries the XOR chunk swizzle)
    const short* esrc[4]; const short* psrc[4]; int rdst[4];
    #pragma unroll
    for (int q = 0; q < 4; q++) {
        const int rb = w * 32 + q * 8, row = rb + rl8;
        const int co = (ch8 ^ (row & 7)) * 8;
        esrc[q] = Eb + (size_t)row * L_DIM + co;
        psrc[q] = Pb + (size_t)row * L_DIM + co;
        rdst[q] = rb * 64;
    }

    // prologue: tile 0 into buffer 0
    #pragma unroll
    for (int q = 0; q < 4; q++) load_lds16(esrc[q], &Es[0][rdst[q]]);
    #pragma unroll
    for (int q = 0; q < 4; q++) load_lds16(psrc[q], &Ps[0][rdst[q]]);
    __syncthreads();

    f32x4 acc[4][8] = {};
    int cur = 0;
    #pragma unroll
    for (int kt = 0; kt < L_DIM; kt += 64) {
        if (kt + 64 < L_DIM) {   // issue next tile's loads before computing current
            #pragma unroll
            for (int q = 0; q < 4; q++)
                load_lds16(esrc[q] + kt + 64, &Es[cur ^ 1][rdst[q]]);
            #pragma unroll
            for (int q = 0; q < 4; q++)
                load_lds16(psrc[q] + kt + 64, &Ps[cur ^ 1][rdst[q]]);
        }
        #pragma unroll
        for (int k2 = 0; k2 < 2; k2++) {
            short8 a[4], b[8];
            #pragma unroll
            for (int i = 0; i < 4; i++) {
                const int m = wm * 64 + i * 16 + l15;
                a[i] = *(const short8*)&Es[cur][m * 64 + ((k2 * 4 + quad) ^ (m & 7)) * 8];
            }
            #pragma unroll
            for (int j = 0; j < 8; j++) {
                const int n = wn * 128 + j * 16 + l15;
                b[j] = *(const short8*)&Ps[cur][n * 64 + ((k2 * 4 + quad) ^ (n & 7)) * 8];
            }
            #pragma unroll
            for (int i = 0; i < 4; i++)
                #pragma unroll
                for (int j = 0; j < 8; j++)
                    acc[i][j] = __builtin_amdgcn_mfma_f32_16x16x32_bf16(a[i], b[j], acc[i][j], 0, 0, 0);
        }
        __syncthreads();   // all waves done reading [cur]; next tile's loads drained
        cur ^= 1;
    }

    // ---- E1: row max over 256 cols ----
    float rm[4][4];
    #pragma unroll
    for (int i = 0; i < 4; i++)
        #pragma unroll
        for (int r = 0; r < 4; r++) {
            float m = acc[i][0][r];
            #pragma unroll
            for (int j = 1; j < 8; j++) m = fmaxf(m, acc[i][j][r]);
            rm[i][r] = m;
        }
    #pragma unroll
    for (int off = 1; off < 16; off <<= 1)
        #pragma unroll
        for (int i = 0; i < 4; i++)
            #pragma unroll
            for (int r = 0; r < 4; r++)
                rm[i][r] = fmaxf(rm[i][r], __shfl_xor(rm[i][r], off, 64));
    if (l15 == 0)
        #pragma unroll
        for (int i = 0; i < 4; i++)
            #pragma unroll
            for (int r = 0; r < 4; r++)
                rmx[wm * 64 + i * 16 + quad * 4 + r][wn] = rm[i][r];
    __syncthreads();

    float mrow[4][4];
    #pragma unroll
    for (int i = 0; i < 4; i++)
        #pragma unroll
        for (int r = 0; r < 4; r++) {
            const float2 v = *(const float2*)rmx[wm * 64 + i * 16 + quad * 4 + r];
            mrow[i][r] = fmaxf(v.x, v.y);
        }

    // ---- E2: row sum of exp ----
    float rs[4][4];
    #pragma unroll
    for (int i = 0; i < 4; i++)
        #pragma unroll
        for (int r = 0; r < 4; r++) {
            float sum = 0.f;
            #pragma unroll
            for (int j = 0; j < 8; j++) sum += __expf(acc[i][j][r] - mrow[i][r]);
            rs[i][r] = sum;
        }
    #pragma unroll
    for (int off = 1; off < 16; off <<= 1)
        #pragma unroll
        for (int i = 0; i < 4; i++)
            #pragma unroll
            for (int r = 0; r < 4; r++)
                rs[i][r] += __shfl_xor(rs[i][r], off, 64);
    if (l15 == 0)
        #pragma unroll
        for (int i = 0; i < 4; i++)
            #pragma unroll
            for (int r = 0; r < 4; r++)
                rsx[wm * 64 + i * 16 + quad * 4 + r][wn] = rs[i][r];
    __syncthreads();

    float lse[4][4];
    #pragma unroll
    for (int i = 0; i < 4; i++)
        #pragma unroll
        for (int r = 0; r < 4; r++) {
            const float2 v = *(const float2*)rsx[wm * 64 + i * 16 + quad * 4 + r];
            lse[i][r] = mrow[i][r] + __logf(v.x + v.y);
        }

    // ---- E3: column argmax (packed u64: ordered-float<<32 | (255-b)) ----
    #pragma unroll
    for (int j = 0; j < 8; j++) {
        unsigned long long best = 0;
        #pragma unroll
        for (int i = 0; i < 4; i++)
            #pragma unroll
            for (int r = 0; r < 4; r++) {
                const int grow = wm * 64 + i * 16 + quad * 4 + r;
                const float v = acc[i][j][r] - lse[i][r];
                unsigned int fb = __float_as_uint(v);
                fb = (fb & 0x80000000u) ? ~fb : (fb | 0x80000000u);
                const unsigned long long p =
                    ((unsigned long long)fb << 32) | (unsigned long long)(255 - grow);
                if (p > best) best = p;          // packed compare: ties -> smallest b
            }
        unsigned long long o;
        o = __shfl_xor(best, 16, 64); if (o > best) best = o;
        o = __shfl_xor(best, 32, 64); if (o > best) best = o;
        if (quad == 0)
            atomicMax(&col_best[((size_t)k * STEPS + s) * B_DIM + wn * 128 + j * 16 + l15], best);
    }

    // ---- diag logp: 1 atomic per block ----
    {
        float dv = 0.f;
        #pragma unroll
        for (int i = 0; i < 4; i++)
            #pragma unroll
            for (int j = 0; j < 8; j++)
                #pragma unroll
                for (int r = 0; r < 4; r++) {
                    const int grow = wm * 64 + i * 16 + quad * 4 + r;
                    const int c = wn * 128 + j * 16 + l15;
                    if (grow == c) dv += acc[i][j][r] - lse[i][r];
                }
        #pragma unroll
        for (int off = 1; off < 64; off <<= 1) dv += __shfl_xor(dv, off, 64);
        if (lane == 0) dred[w] = dv;
    }
    __syncthreads();
    if (t == 0) {
        float dv = 0.f;
        #pragma unroll
        for (int i = 0; i < 8; i++) dv += dred[i];
        atomicAdd(diag_accum, dv);
    }
}

// count + finalize merged: last block (device-scope done counter) writes out.
__global__ void count_finalize(const unsigned long long* __restrict__ col_best,
                               int* __restrict__ correct_accum,
                               float* __restrict__ diag_accum,
                               unsigned int* __restrict__ done,
                               float* __restrict__ out) {
    __shared__ int red[256];
    const int t = threadIdx.x;
    int cnt = 0;
    for (int i = blockIdx.x * 256 + t; i < DENOM; i += gridDim.x * 256) {
        const int c = i & (B_DIM - 1);
        const int b = 255 - (int)(col_best[i] & 0xFFFFFFFFull);
        cnt += (b == c) ? 1 : 0;
    }
    red[t] = cnt;
    __syncthreads();
    for (int off = 128; off > 0; off >>= 1) {
        if (t < off) red[t] += red[t + off];
        __syncthreads();
    }
    if (t == 0) {
        atomicAdd(correct_accum, red[0]);
        __threadfence();
        if (atomicAdd(done, 1u) == gridDim.x - 1) {
            const int   c = atomicAdd(correct_accum, 0);   // coherent read
            const float d = atomicAdd(diag_accum, 0.0f);   // coherent read
            const float denom = (float)DENOM;
            out[0] = (float)c / denom;   // accuracy
            out[1] = -d / denom;         // loss
        }
    }
}

extern "C" void kernel_launch(void* const* d_in, const int* in_sizes, int n_in,
                              void* d_out, int out_size, void* d_ws, size_t ws_size,
                              hipStream_t stream) {
    const float* encoded_x = (const float*)d_in[0];
    const float* context   = (const float*)d_in[1];
    const float* Wk        = (const float*)d_in[2];
    float* out = (float*)d_out;

    const size_t enc_elems = (size_t)S_DIM * B_DIM * L_DIM;    // 16,777,216
    const size_t ctx_elems = (size_t)STEPS * B_DIM * L_DIM;    // 13,500,416
    const size_t wk_elems  = (size_t)K_DIM * L_DIM * L_DIM;    //  2,097,152
    const size_t pred_k_bytes = ctx_elems * 2;                 // 27.0 MB per k

    char* ws = (char*)d_ws;
    short* encbf = (short*)ws;                                          // 33.6 MB
    short* ctxbf = (short*)(ws + enc_elems * 2);                        // 27.0 MB
    short* wkbf  = (short*)(ws + (enc_elems + ctx_elems) * 2);          //  4.2 MB
    const size_t off = (enc_elems + ctx_elems + wk_elems) * 2;
    unsigned long long* col_best = (unsigned long long*)(ws + off);     // 1.69 MB
    float* diag_accum    = (float*)(ws + off + (size_t)DENOM * 8);
    int*   correct_accum = (int*)  (ws + off + (size_t)DENOM * 8 + 4);
    unsigned int* done   = (unsigned int*)(ws + off + (size_t)DENOM * 8 + 8);
    const size_t fixed = off + (size_t)DENOM * 8 + 64;
    short* pred = (short*)(ws + fixed);

    // g=8: single gemm + single sim dispatch when workspace allows.
    int g = K_DIM;
    while (g > 1 && fixed + (size_t)g * pred_k_bytes > ws_size) g >>= 1;

    // convert also zeroes col_best/diag/correct/done (replaces memset dispatch)
    convert_all<<<2048, 256, 0, stream>>>(encoded_x, context + (size_t)T_IN * B_DIM * L_DIM,
                                          Wk, encbf, ctxbf, wkbf, col_best);

    const dim3 g1(4 * g, (STEPS * B_DIM) / 128);    // (4g, 206): x = (kin,cn)
    const dim3 g2(STEPS, g);                        // (103, g): full 256x256 per block
    for (int k0 = 0; k0 < K_DIM; k0 += g) {
        gemm_bf16<<<g1, 256, 0, stream>>>(ctxbf, wkbf + (size_t)k0 * L_DIM * L_DIM, pred);
        sim_phase<<<g2, 512, 0, stream>>>(encbf, pred, k0, col_best, diag_accum);
    }
    count_finalize<<<64, 256, 0, stream>>>(col_best, correct_accum, diag_accum, done, out);
}